// Round 1
// baseline (299.690 us; speedup 1.0000x reference)
//
#include <hip/hip_runtime.h>

#define CUT 512
#define HH 4096
#define WW 4096

// ---------------------------------------------------------------------------
// Bilinear tap helper: replicate the reference formula EXACTLY in fp32:
//   t  = ((i + 0.5) * s) / 512 - 0.5
//   y  = clip(off + t, off, off + s - 1)
//   y0 = floor(y); y1 = min(y0 + 1, off + size - 1); wy = y - y0
// ---------------------------------------------------------------------------
__device__ __forceinline__ void coord(int i, int off, int size, float s,
                                      int& c0, int& c1, float& w) {
    float t = ((i + 0.5f) * s) / 512.0f - 0.5f;
    float offf = (float)off;
    float v = off + t;                       // int + float, like the reference
    v = fminf(fmaxf(v, offf), offf + s - 1.0f);
    c0 = (int)floorf(v);
    c1 = min(c0 + 1, off + size - 1);
    w = v - (float)c0;
}

__device__ __forceinline__ float bilerp(const float* __restrict__ p,
                                        int y0, int y1, int x0, int x1,
                                        float wy, float wx) {
    float a  = p[(size_t)y0 * WW + x0];
    float b  = p[(size_t)y0 * WW + x1];
    float c  = p[(size_t)y1 * WW + x0];
    float d  = p[(size_t)y1 * WW + x1];
    float top = a * (1.0f - wx) + b * wx;
    float bot = c * (1.0f - wx) + d * wx;
    return top * (1.0f - wy) + bot * wy;
}

// ---------------------------------------------------------------------------
// Overview: one resize of the full image -> slots 0 (full), 1 (gray),
// 2 (x-flip), 3 (gray of flip == gray flipped).
// ---------------------------------------------------------------------------
__global__ void overview_kernel(const float* __restrict__ img,
                                float* __restrict__ out) {
    int j = blockIdx.x * blockDim.x + threadIdx.x;   // output x
    int i = blockIdx.y;                              // output y
    if (j >= CUT) return;

    const int size = 4096;
    const float s = 4096.0f;
    int y0, y1, x0, x1;
    float wy, wx;
    coord(i, 0, size, s, y0, y1, wy);
    coord(j, 0, size, s, x0, x1, wx);

    float v[3];
#pragma unroll
    for (int c = 0; c < 3; ++c) {
        const float* p = img + (size_t)c * HH * WW;
        v[c] = bilerp(p, y0, y1, x0, x1, wy, wx);
    }
    float gray = v[0] * 0.2989f + v[1] * 0.587f + v[2] * 0.114f;

    const size_t imgStride = (size_t)3 * CUT * CUT;   // one output image
    const size_t chStride  = (size_t)CUT * CUT;
    size_t px  = (size_t)i * CUT + j;
    size_t pxf = (size_t)i * CUT + (CUT - 1 - j);     // flipped x

#pragma unroll
    for (int c = 0; c < 3; ++c) {
        out[0 * imgStride + c * chStride + px]  = v[c];
        out[1 * imgStride + c * chStride + px]  = gray;
        out[2 * imgStride + c * chStride + pxf] = v[c];
        out[3 * imgStride + c * chStride + pxf] = gray;
    }
}

// ---------------------------------------------------------------------------
// Inner crops: 12 images, slot index 4+k. k==0 is gray'd across channels.
// ---------------------------------------------------------------------------
__global__ void inner_kernel(const float* __restrict__ img,
                             const int* __restrict__ sizes,
                             const int* __restrict__ offy,
                             const int* __restrict__ offx,
                             float* __restrict__ out) {
    int k = blockIdx.z;                              // crop index 0..11
    int j = blockIdx.x * blockDim.x + threadIdx.x;   // output x
    int i = blockIdx.y;                              // output y
    if (j >= CUT) return;

    int size = sizes[k];
    int oy = offy[k];
    int ox = offx[k];
    float s = (float)size;

    int y0, y1, x0, x1;
    float wy, wx;
    coord(i, oy, size, s, y0, y1, wy);
    coord(j, ox, size, s, x0, x1, wx);

    float v[3];
#pragma unroll
    for (int c = 0; c < 3; ++c) {
        const float* p = img + (size_t)c * HH * WW;
        v[c] = bilerp(p, y0, y1, x0, x1, wy, wx);
    }

    const size_t imgStride = (size_t)3 * CUT * CUT;
    const size_t chStride  = (size_t)CUT * CUT;
    size_t base = (size_t)(4 + k) * imgStride;
    size_t px = (size_t)i * CUT + j;

    if (k == 0) {
        float gray = v[0] * 0.2989f + v[1] * 0.587f + v[2] * 0.114f;
#pragma unroll
        for (int c = 0; c < 3; ++c)
            out[base + c * chStride + px] = gray;
    } else {
#pragma unroll
        for (int c = 0; c < 3; ++c)
            out[base + c * chStride + px] = v[c];
    }
}

extern "C" void kernel_launch(void* const* d_in, const int* in_sizes, int n_in,
                              void* d_out, int out_size, void* d_ws, size_t ws_size,
                              hipStream_t stream) {
    const float* img  = (const float*)d_in[0];
    // d_in[1] = t (unused by the reference)
    const int* sizes  = (const int*)d_in[2];
    const int* offy   = (const int*)d_in[3];
    const int* offx   = (const int*)d_in[4];
    float* out = (float*)d_out;

    dim3 block(256, 1, 1);
    dim3 gridOv((CUT + 255) / 256, CUT, 1);
    hipLaunchKernelGGL(overview_kernel, gridOv, block, 0, stream, img, out);

    dim3 gridIn((CUT + 255) / 256, CUT, 12);
    hipLaunchKernelGGL(inner_kernel, gridIn, block, 0, stream,
                       img, sizes, offy, offx, out);
}